// Round 10
// baseline (386.674 us; speedup 1.0000x reference)
//
#include <hip/hip_runtime.h>

// GINConv pipeline. R9/R10: R7 (direct global, strided) and R8 (LDS-staged,
// 2 blk/CU barrier-serialized) were both fragment-SUPPLY latency-bound
// (MfmaUtil ~3.7%, VALUBusy ~7%, occ 17%). Fix: store A/B pre-tiled in
// EXACT MFMA fragment order — per 16-row block: [ks][kg][lr][8bf16],
// hi plane then lo plane. One fragment load = 64 lanes x 16B = contiguous
// 1KB. mlp kernels: NO LDS, NO barriers, just coalesced loads + MFMA.
// R10 fix vs R9: bnrelu_split is workgroup-diagonal (1 WG per 16-row block,
// read->barrier->write) because h1 and a2p alias the same ws region and the
// tiled write span != read span per thread (2-WG-per-block race in R9).
// Numerics unchanged (triple-MFMA hi/lo, lo*lo dropped).
//
// Tiled offset for element (row r, k), K columns, ushort units:
//   P = (K/32)*512 (plane), blk = r>>4
//   hi: blk*2P + (k>>5)*512 + ((k>>3)&3)*128 + (r&15)*8 + (k&7);  lo: +P
//
// NOTE: harness delivers integer inputs as int32 — edge_index is const int*.

#define N_NODES 50000
#define N_EDGES 800000
#define D_IN    128
#define D_HID   256
#define D_OUT   128
#define BN_EPS  1e-5f

#define NBLK_SCAN 49   // ceil(50000 / 1024)
#define GX_MLP    782  // ceil(50000 / 64)
#define NRBLK     3128 // ceil(50048 / 16) row blocks (padded past grid)

typedef __attribute__((ext_vector_type(8))) __bf16 bf16x8;
typedef __attribute__((ext_vector_type(4))) float  f32x4;
typedef __attribute__((ext_vector_type(8))) unsigned short us8;

__device__ __forceinline__ void split_bf16(float v, unsigned short& h, unsigned short& l)
{
    __bf16 bh = (__bf16)v;
    float  r  = v - (float)bh;
    __bf16 bl = (__bf16)r;
    h = __builtin_bit_cast(unsigned short, bh);
    l = __builtin_bit_cast(unsigned short, bl);
}

// ---------------- CSR build ----------------

__global__ __launch_bounds__(256) void deg_kernel(
    const int* __restrict__ ei, int* __restrict__ deg)
{
    const int e = blockIdx.x * 256 + threadIdx.x;
    if (e >= N_EDGES) return;
    atomicAdd(&deg[ei[N_EDGES + e]], 1);
}

__global__ __launch_bounds__(256) void scan1_kernel(
    const int* __restrict__ deg, int* __restrict__ bsum)
{
    __shared__ int ws[4];
    const int t = threadIdx.x;
    const int i0 = blockIdx.x * 1024 + t * 4;
    int s = 0;
    if (i0 + 3 < N_NODES) {
        const int4 d = *(const int4*)(deg + i0);
        s = d.x + d.y + d.z + d.w;
    } else {
        #pragma unroll
        for (int q = 0; q < 4; ++q) if (i0 + q < N_NODES) s += deg[i0 + q];
    }
    #pragma unroll
    for (int d = 32; d > 0; d >>= 1) s += __shfl_down(s, d);
    if ((t & 63) == 0) ws[t >> 6] = s;
    __syncthreads();
    if (t == 0) bsum[blockIdx.x] = ws[0] + ws[1] + ws[2] + ws[3];
}

__global__ __launch_bounds__(64) void scan2_kernel(
    int* __restrict__ bsum, int* __restrict__ off)
{
    const int lane = threadIdx.x;
    const int v = (lane < NBLK_SCAN) ? bsum[lane] : 0;
    int incl = v;
    #pragma unroll
    for (int d = 1; d < 64; d <<= 1) {
        const int up = __shfl_up(incl, d);
        if (lane >= d) incl += up;
    }
    if (lane < NBLK_SCAN) bsum[lane] = incl - v;
    if (lane == 0) off[N_NODES] = N_EDGES;
}

__global__ __launch_bounds__(256) void scan3_kernel(
    const int* __restrict__ deg, const int* __restrict__ bsum,
    int* __restrict__ off, int* __restrict__ cursor)
{
    __shared__ int ws[4];
    const int t = threadIdx.x;
    const int lane = t & 63, wid = t >> 6;
    const int i0 = blockIdx.x * 1024 + t * 4;
    int4 d = make_int4(0, 0, 0, 0);
    if (i0 + 3 < N_NODES) {
        d = *(const int4*)(deg + i0);
    } else {
        if (i0 + 0 < N_NODES) d.x = deg[i0 + 0];
        if (i0 + 1 < N_NODES) d.y = deg[i0 + 1];
        if (i0 + 2 < N_NODES) d.z = deg[i0 + 2];
    }
    const int tsum = d.x + d.y + d.z + d.w;
    int incl = tsum;
    #pragma unroll
    for (int dd = 1; dd < 64; dd <<= 1) {
        const int up = __shfl_up(incl, dd);
        if (lane >= dd) incl += up;
    }
    if (lane == 63) ws[wid] = incl;
    __syncthreads();
    int wbase = 0;
    for (int w = 0; w < wid; ++w) wbase += ws[w];
    const int e = bsum[blockIdx.x] + wbase + incl - tsum;
    int4 o;
    o.x = e; o.y = e + d.x; o.z = o.y + d.y; o.w = o.z + d.z;
    if (i0 + 3 < N_NODES) {
        *(int4*)(off + i0)    = o;
        *(int4*)(cursor + i0) = o;
    } else {
        if (i0 + 0 < N_NODES) { off[i0 + 0] = o.x; cursor[i0 + 0] = o.x; }
        if (i0 + 1 < N_NODES) { off[i0 + 1] = o.y; cursor[i0 + 1] = o.y; }
        if (i0 + 2 < N_NODES) { off[i0 + 2] = o.z; cursor[i0 + 2] = o.z; }
    }
}

__global__ __launch_bounds__(256) void fill_kernel(
    const int* __restrict__ ei, int* __restrict__ cursor, int* __restrict__ esrc)
{
    const int e = blockIdx.x * 256 + threadIdx.x;
    if (e >= N_EDGES) return;
    const int pos = atomicAdd(&cursor[ei[N_EDGES + e]], 1);
    esrc[pos] = ei[e];
}

// ---------------- gather + self + bf16 split (fused, tiled output) ----------
// Lane handles channels k=2*lane, 2*lane+1 (K=128): ks=lane>>4,
// kg=(lane>>2)&3, e=(2*lane)&7. Plane P=2048 ushorts, block=4096.

__global__ __launch_bounds__(256) void gather_kernel(
    const float* __restrict__ x, const int* __restrict__ off,
    const int* __restrict__ esrc, unsigned short* __restrict__ xp)
{
    const int gtid = blockIdx.x * 256 + threadIdx.x;
    const int node = gtid >> 6;
    const int lane = gtid & 63;
    if (node >= N_NODES) return;
    const int e0 = off[node], e1 = off[node + 1];
    const float2 xv = ((const float2*)(x + (size_t)node * D_IN))[lane];
    float2 acc = xv;                               // (1+eps)*x with eps=0
    for (int e = e0; e < e1; e += 64) {
        const int n = min(64, e1 - e);
        const int myS = (lane < n) ? esrc[e + lane] : 0;
        for (int j = 0; j < n; ++j) {
            const int s = __shfl(myS, j);
            const float2 v = ((const float2*)(x + (size_t)s * D_IN))[lane];
            acc.x += v.x;
            acc.y += v.y;
        }
    }
    unsigned short h0, l0, h1_, l1_;
    split_bf16(acc.x, h0, l0);
    split_bf16(acc.y, h1_, l1_);
    const size_t o = (size_t)(node >> 4) * 4096 + (lane >> 4) * 512
                   + ((lane >> 2) & 3) * 128 + (node & 15) * 8 + ((2 * lane) & 7);
    *(ushort2*)&xp[o]        = make_ushort2(h0, h1_);
    *(ushort2*)&xp[o + 2048] = make_ushort2(l0, l1_);
}

// ---------------- W transpose + split (tiled output) ----------------
// src [K][N] f32 -> tiled-by-n planes, P=(K/32)*512.

__global__ __launch_bounds__(256) void wsplit_kernel(
    const float* __restrict__ src, unsigned short* __restrict__ dst,
    int K, int N)
{
    __shared__ float tile[64][65];
    const int k0 = blockIdx.x * 64, n0 = blockIdx.y * 64;
    const int t = threadIdx.x;
    const int tr = t >> 4, tc4 = (t & 15) * 4;
    const int P = (K >> 5) * 512;
    #pragma unroll
    for (int i = 0; i < 4; ++i) {
        const int r = tr + i * 16;
        *(float4*)&tile[r][tc4] = *(const float4*)(src + (size_t)(k0 + r) * N + n0 + tc4);
    }
    __syncthreads();
    #pragma unroll
    for (int i = 0; i < 4; ++i) {
        const int n = n0 + tr + i * 16;
        ushort4 hh, ll;
        split_bf16(tile[tc4 + 0][tr + i * 16], hh.x, ll.x);
        split_bf16(tile[tc4 + 1][tr + i * 16], hh.y, ll.y);
        split_bf16(tile[tc4 + 2][tr + i * 16], hh.z, ll.z);
        split_bf16(tile[tc4 + 3][tr + i * 16], hh.w, ll.w);
        const int kk = k0 + tc4;
        const size_t o = (size_t)(n >> 4) * 2 * P + (kk >> 5) * 512
                       + ((kk >> 3) & 3) * 128 + (n & 15) * 8 + (kk & 7);
        *(ushort4*)&dst[o]     = hh;
        *(ushort4*)&dst[o + P] = ll;
    }
}

// ---------------- BN + ReLU + split (tiled, in-place, WG-diagonal) --------
// h1 (fp32 row-major) and a2_out (tiled planes) ALIAS the same region.
// One WG per 16-row block: the block's read byte-range == write byte-range
// ([blk*16KB, +16KB)); barrier separates all reads from all writes.
// 256 threads x 2 items; item = (rowin, cb): rowin=item>>5, cb=item&31.
// Tiled dst (K=256, P=4096): blk*8192 + (cb>>2)*512 + (cb&3)*128 + rowin*8.

__global__ __launch_bounds__(256) void bnrelu_split_kernel(
    const float* h1_in, unsigned short* a2_out,
    const float* __restrict__ aco, const float* __restrict__ cco)
{
    const int blk = blockIdx.x;
    const int tid = threadIdx.x;
    us8 hi[2], lo[2];
    int dsto[2];
    #pragma unroll
    for (int ii = 0; ii < 2; ++ii) {
        const int item  = tid + ii * 256;
        const int rowin = item >> 5, cb = item & 31;
        const int row   = blk * 16 + rowin;
        const float* p = h1_in + (size_t)row * 256 + cb * 8;
        const float4 v0 = *(const float4*)p;
        const float4 v1 = *(const float4*)(p + 4);
        const float4 a0 = *(const float4*)(aco + cb * 8);
        const float4 a1 = *(const float4*)(aco + cb * 8 + 4);
        const float4 c0 = *(const float4*)(cco + cb * 8);
        const float4 c1 = *(const float4*)(cco + cb * 8 + 4);
        float r[8];
        r[0] = fmaxf(fmaf(v0.x, a0.x, c0.x), 0.f);
        r[1] = fmaxf(fmaf(v0.y, a0.y, c0.y), 0.f);
        r[2] = fmaxf(fmaf(v0.z, a0.z, c0.z), 0.f);
        r[3] = fmaxf(fmaf(v0.w, a0.w, c0.w), 0.f);
        r[4] = fmaxf(fmaf(v1.x, a1.x, c1.x), 0.f);
        r[5] = fmaxf(fmaf(v1.y, a1.y, c1.y), 0.f);
        r[6] = fmaxf(fmaf(v1.z, a1.z, c1.z), 0.f);
        r[7] = fmaxf(fmaf(v1.w, a1.w, c1.w), 0.f);
        #pragma unroll
        for (int q = 0; q < 8; ++q) {
            unsigned short h, l;
            split_bf16(r[q], h, l);
            hi[ii][q] = h; lo[ii][q] = l;
        }
        dsto[ii] = blk * 8192 + (cb >> 2) * 512 + (cb & 3) * 128 + rowin * 8;
    }
    __syncthreads();
    #pragma unroll
    for (int ii = 0; ii < 2; ++ii) {
        *(us8*)&a2_out[dsto[ii]]        = hi[ii];
        *(us8*)&a2_out[dsto[ii] + 4096] = lo[ii];
    }
}

// ---------------- MFMA GEMMs: fragment-order global loads, no LDS ----------
// MODE 1: h1 = (x+agg) @ W1 + b1 (+ BN col stats)   A=xp  B=w1t  K=128 N=256
// MODE 2: out = a2 @ W2 + b2                        A=a2p B=w2t  K=256 N=128
// Block: 4 waves 2x2, tile 64x64; wave 32x32 = 2x2 mfma_f32_16x16x32_bf16.
// One fragment load = 64 lanes x 16B = contiguous 1KB (lane off kg*128+lr*8).
// OOB A-row-blocks (3125..3127) read benign 0xAA poison inside allocation;
// MFMA row-independence confines it to store-masked rows.

template<int MODE>
__global__ __launch_bounds__(256) void mlp_kernel(
    const unsigned short* __restrict__ Ap, const unsigned short* __restrict__ Bp,
    const float* __restrict__ bias, float* __restrict__ outp,
    float* __restrict__ ssum, float* __restrict__ ssq)
{
    constexpr int K   = (MODE == 1) ? 128 : 256;
    constexpr int NV  = (MODE == 1) ? 256 : 128;
    constexpr int NKS = K / 32;
    constexpr int P   = NKS * 512;        // plane size (ushorts)
    const int tid  = threadIdx.x;
    const int lane = tid & 63;
    const int w    = tid >> 6;
    const int wr   = w >> 1, wc = w & 1;
    const int lr   = lane & 15, kg = lane >> 4;
    const int i0   = blockIdx.x * 64;
    const int jb   = blockIdx.y * 64;
    const int fo   = kg * 128 + lr * 8;   // lane offset within a fragment KB

    const unsigned short* Ab[2];
    const unsigned short* Bb[2];
    #pragma unroll
    for (int mi = 0; mi < 2; ++mi)
        Ab[mi] = Ap + (size_t)((i0 + wr * 32 + mi * 16) >> 4) * (2 * P) + fo;
    #pragma unroll
    for (int ni = 0; ni < 2; ++ni)
        Bb[ni] = Bp + (size_t)((jb + wc * 32 + ni * 16) >> 4) * (2 * P) + fo;

    f32x4 acc[2][2] = {};

    #pragma unroll
    for (int ks = 0; ks < NKS; ++ks) {
        const int o = ks * 512;
        bf16x8 ah[2], al[2], bh[2], bl[2];
        #pragma unroll
        for (int mi = 0; mi < 2; ++mi) {
            ah[mi] = *(const bf16x8*)(Ab[mi] + o);
            al[mi] = *(const bf16x8*)(Ab[mi] + o + P);
        }
        #pragma unroll
        for (int ni = 0; ni < 2; ++ni) {
            bh[ni] = *(const bf16x8*)(Bb[ni] + o);
            bl[ni] = *(const bf16x8*)(Bb[ni] + o + P);
        }
        #pragma unroll
        for (int mi = 0; mi < 2; ++mi)
            #pragma unroll
            for (int ni = 0; ni < 2; ++ni) {
                acc[mi][ni] = __builtin_amdgcn_mfma_f32_16x16x32_bf16(
                    ah[mi], bh[ni], acc[mi][ni], 0, 0, 0);
                acc[mi][ni] = __builtin_amdgcn_mfma_f32_16x16x32_bf16(
                    ah[mi], bl[ni], acc[mi][ni], 0, 0, 0);
                acc[mi][ni] = __builtin_amdgcn_mfma_f32_16x16x32_bf16(
                    al[mi], bh[ni], acc[mi][ni], 0, 0, 0);
            }
    }

    // ---- epilogue: C/D layout col=lane&15, row=(lane>>4)*4+reg (m89) ----
    #pragma unroll
    for (int ni = 0; ni < 2; ++ni) {
        const int col = jb + wc * 32 + ni * 16 + lr;
        const float bv = bias[col];
        if (MODE == 1) {
            float s = 0.f, sq = 0.f;
            #pragma unroll
            for (int mi = 0; mi < 2; ++mi)
                #pragma unroll
                for (int r = 0; r < 4; ++r) {
                    const int row = i0 + wr * 32 + mi * 16 + kg * 4 + r;
                    if (row < N_NODES) {
                        const float hv = acc[mi][ni][r] + bv;
                        outp[(size_t)row * NV + col] = hv;
                        s += hv; sq += hv * hv;
                    }
                }
            s  += __shfl_xor(s, 16);  s  += __shfl_xor(s, 32);
            sq += __shfl_xor(sq, 16); sq += __shfl_xor(sq, 32);
            if (kg == 0) {
                atomicAdd(&ssum[col], s);
                atomicAdd(&ssq[col], sq);
            }
        } else {
            #pragma unroll
            for (int mi = 0; mi < 2; ++mi)
                #pragma unroll
                for (int r = 0; r < 4; ++r) {
                    const int row = i0 + wr * 32 + mi * 16 + kg * 4 + r;
                    if (row < N_NODES)
                        outp[(size_t)row * NV + col] = acc[mi][ni][r] + bv;
                }
        }
    }
}

__global__ __launch_bounds__(256) void bnfinal_kernel(
    const float* __restrict__ ssum, const float* __restrict__ ssq,
    const float* __restrict__ gamma, const float* __restrict__ beta,
    float* __restrict__ aco, float* __restrict__ cco)
{
    const int j = threadIdx.x;
    const float inv_n = 1.0f / (float)N_NODES;
    const float mean = ssum[j] * inv_n;
    const float var  = ssq[j] * inv_n - mean * mean;
    const float rstd = rsqrtf(var + BN_EPS);
    const float a = rstd * gamma[j];
    aco[j] = a;
    cco[j] = beta[j] - mean * a;
}

extern "C" void kernel_launch(void* const* d_in, const int* in_sizes, int n_in,
                              void* d_out, int out_size, void* d_ws, size_t ws_size,
                              hipStream_t stream)
{
    const float* x     = (const float*)d_in[0];
    const int*   ei    = (const int*)d_in[1];      // int32 per harness contract
    const float* W1    = (const float*)d_in[2];
    const float* b1    = (const float*)d_in[3];
    const float* gamma = (const float*)d_in[4];
    const float* beta  = (const float*)d_in[5];
    const float* W2    = (const float*)d_in[6];
    const float* b2    = (const float*)d_in[7];
    float* out = (float*)d_out;

    // ws layout (~81 MB):
    // xp  tiled [3128 blk x 4096 ushort]  25.6 MB
    // a2p tiled [3128 blk x 8192 ushort]  51.25 MB (aliases h1 fp32 [50000x256])
    // w1t [65536 us] | w2t [65536 us] | ssum/ssq/aco/cco | deg/off/cursor
    // | esrc[E] | bsum[64]
    unsigned short* xp  = (unsigned short*)d_ws;
    unsigned short* a2p = xp + (size_t)NRBLK * 4096;
    float* h1           = (float*)a2p;
    unsigned short* w1t = a2p + (size_t)NRBLK * 8192;
    unsigned short* w2t = w1t + 65536;
    float* ssum = (float*)(w2t + 65536);
    float* ssq  = ssum + D_HID;
    float* aco  = ssq  + D_HID;
    float* cco  = aco  + D_HID;
    int* deg    = (int*)(cco + D_HID);
    int* off    = deg + N_NODES;
    int* cursor = off + N_NODES + 1;
    int* esrc   = cursor + N_NODES;
    int* bsum   = esrc + N_EDGES;

    hipMemsetAsync(deg,  0, N_NODES * sizeof(int), stream);
    hipMemsetAsync(ssum, 0, 2 * D_HID * sizeof(float), stream);

    wsplit_kernel<<<dim3(2, 4), 256, 0, stream>>>(W1, w1t, D_IN, D_HID);
    wsplit_kernel<<<dim3(4, 2), 256, 0, stream>>>(W2, w2t, D_HID, D_OUT);

    deg_kernel<<<(N_EDGES + 255) / 256, 256, 0, stream>>>(ei, deg);
    scan1_kernel<<<NBLK_SCAN, 256, 0, stream>>>(deg, bsum);
    scan2_kernel<<<1, 64, 0, stream>>>(bsum, off);
    scan3_kernel<<<NBLK_SCAN, 256, 0, stream>>>(deg, bsum, off, cursor);
    fill_kernel<<<(N_EDGES + 255) / 256, 256, 0, stream>>>(ei, cursor, esrc);
    gather_kernel<<<(N_NODES * 64 + 255) / 256, 256, 0, stream>>>(x, off, esrc, xp);

    mlp_kernel<1><<<dim3(GX_MLP, D_HID / 64), 256, 0, stream>>>(
        xp, w1t, b1, h1, ssum, ssq);

    bnfinal_kernel<<<1, D_HID, 0, stream>>>(ssum, ssq, gamma, beta, aco, cco);

    bnrelu_split_kernel<<<N_NODES / 16, 256, 0, stream>>>(h1, a2p, aco, cco);

    mlp_kernel<2><<<dim3(GX_MLP, D_OUT / 64), 256, 0, stream>>>(
        a2p, w2t, b2, out, nullptr, nullptr);
}